// Round 7
// baseline (9066.483 us; speedup 1.0000x reference)
//
#include <hip/hip_runtime.h>
#include <hip/hip_bf16.h>

#define BB 32
#define TT 128
#define PP 196
#define ENC 2048
#define DEC 512
#define ATT 512
#define EMB 512
#define VV 10000
#define G4 2048   // 4*DEC
#define KX 2560   // EMB+ENC

typedef unsigned short u16;
typedef unsigned int u32;
typedef __attribute__((ext_vector_type(8))) short short8;
typedef __attribute__((ext_vector_type(4))) float f32x4;

__device__ __forceinline__ float bf2f(u16 u) { return __uint_as_float(((u32)u) << 16); }
__device__ __forceinline__ u16 f2bf(float f) {
  u32 x = __float_as_uint(f);
  u32 r = (x + 0x7fffu + ((x >> 16) & 1u)) >> 16;
  return (u16)r;
}
__device__ __forceinline__ void unpack8(uint4 v, float* f) {
  f[0] = __uint_as_float(v.x << 16); f[1] = __uint_as_float(v.x & 0xffff0000u);
  f[2] = __uint_as_float(v.y << 16); f[3] = __uint_as_float(v.y & 0xffff0000u);
  f[4] = __uint_as_float(v.z << 16); f[5] = __uint_as_float(v.z & 0xffff0000u);
  f[6] = __uint_as_float(v.w << 16); f[7] = __uint_as_float(v.w & 0xffff0000u);
}
__device__ __forceinline__ void load8(const float* __restrict__ p, float* f) {
  float4 a = ((const float4*)p)[0];
  float4 b = ((const float4*)p)[1];
  f[0] = a.x; f[1] = a.y; f[2] = a.z; f[3] = a.w;
  f[4] = b.x; f[5] = b.y; f[6] = b.z; f[7] = b.w;
}
__device__ __forceinline__ float sigf(float x) { return 1.0f / (1.0f + __expf(-x)); }
__device__ __forceinline__ short8 ld_frag(const u16* __restrict__ p) {
  union { uint4 u; short8 s; } cv;
  cv.u = *(const uint4*)p;
  return cv.s;
}

// ---------- one-time f32 -> bf16 conversion ----------
__global__ __launch_bounds__(256) void k_cvt(const float* __restrict__ src, u16* __restrict__ dst, int n) {
  int i0 = (blockIdx.x * 256 + threadIdx.x) * 8;
  if (i0 >= n) return;
  float f[8]; load8(src + i0, f);
  u16 o[8];
#pragma unroll
  for (int u = 0; u < 8; u++) o[u] = f2bf(f[u]);
  *(uint4*)(dst + i0) = *(const uint4*)o;
}

// ---------- mean over p: imgs_bf -> mean_bf (32 x 2048 bf16) ----------
__global__ __launch_bounds__(256) void k_mean(const u16* __restrict__ imgs_bf, u16* __restrict__ mean_bf) {
  int b = blockIdx.x >> 2, chunk = blockIdx.x & 3;
  int ch0 = chunk * 512 + threadIdx.x * 2;
  const u32* base = (const u32*)(imgs_bf + (size_t)b * PP * ENC + ch0);
  float a0 = 0.f, a1 = 0.f;
#pragma unroll 4
  for (int p = 0; p < PP; p++) {
    u32 u = base[(size_t)p * (ENC / 2)];
    a0 += __uint_as_float(u << 16);
    a1 += __uint_as_float(u & 0xffff0000u);
  }
  const float inv = 1.0f / PP;
  u16 o[2] = { f2bf(a0 * inv), f2bf(a1 * inv) };
  *(u32*)(mean_bf + b * ENC + ch0) = *(const u32*)o;
}

// ---------- init via MFMA: [h0;c0] = mean @ [ihW;icW]^T + b ----------
__global__ __launch_bounds__(64) void k_init2(const u16* __restrict__ W2_bf,
    const float* __restrict__ ihb, const float* __restrict__ icb,
    const u16* __restrict__ mean_bf, u16* __restrict__ h_bf, float* __restrict__ c) {
  int lane = threadIdx.x;
  int j0 = blockIdx.x * 16;
  int m = lane & 15, quad = lane >> 4;
  const u16* arow = W2_bf + (size_t)(j0 + m) * ENC + quad * 8;
  const u16* xb0 = mean_bf + (size_t)m * ENC + quad * 8;
  const u16* xb1 = mean_bf + (size_t)(16 + m) * ENC + quad * 8;
  f32x4 acc0 = {0.f,0.f,0.f,0.f}, acc1 = {0.f,0.f,0.f,0.f};
  for (int k = 0; k < ENC; k += 32) {
    short8 a = ld_frag(arow + k);
    short8 x0 = ld_frag(xb0 + k);
    short8 x1 = ld_frag(xb1 + k);
    acc0 = __builtin_amdgcn_mfma_f32_16x16x32_bf16(a, x0, acc0, 0, 0, 0);
    acc1 = __builtin_amdgcn_mfma_f32_16x16x32_bf16(a, x1, acc1, 0, 0, 0);
  }
  int jj = j0 + quad * 4;
  int b0 = m, b1 = 16 + m;
#pragma unroll
  for (int r = 0; r < 4; r++) {
    int j = jj + r;
    if (j < 512) {
      float bia = ihb[j];
      h_bf[b0 * DEC + j] = f2bf(acc0[r] + bia);
      h_bf[b1 * DEC + j] = f2bf(acc1[r] + bia);
    } else {
      int g = j - 512;
      float bia = icb[g];
      c[b0 * DEC + g] = acc0[r] + bia;
      c[b1 * DEC + g] = acc1[r] + bia;
    }
  }
}

// ---------- att1 via MFMA: imgs_bf(6272x2048) @ encW^T -> att1 bf16 ----------
__global__ __launch_bounds__(256) void k_att1(const u16* __restrict__ imgs_bf,
    const u16* __restrict__ encW_bf, const float* __restrict__ encb, u16* __restrict__ att1) {
  int tid = threadIdx.x;
  int wave = tid >> 6, lane = tid & 63;
  int m0 = blockIdx.x * 32;
  int lm = lane & 15, quad = lane >> 4;
  const u16* b0p = imgs_bf + (size_t)(m0 + lm) * ENC + quad * 8;
  const u16* b1p = imgs_bf + (size_t)(m0 + 16 + lm) * ENC + quad * 8;
  const u16* arow = encW_bf + (size_t)(wave * 128 + lm) * ENC + quad * 8;
  f32x4 acc[8][2];
#pragma unroll
  for (int i = 0; i < 8; i++) { acc[i][0] = (f32x4){0.f,0.f,0.f,0.f}; acc[i][1] = (f32x4){0.f,0.f,0.f,0.f}; }
  for (int k = 0; k < ENC; k += 32) {
    short8 B0 = ld_frag(b0p + k);
    short8 B1 = ld_frag(b1p + k);
#pragma unroll
    for (int i = 0; i < 8; i++) {
      short8 A = ld_frag(arow + (size_t)i * 16 * ENC + k);
      acc[i][0] = __builtin_amdgcn_mfma_f32_16x16x32_bf16(A, B0, acc[i][0], 0, 0, 0);
      acc[i][1] = __builtin_amdgcn_mfma_f32_16x16x32_bf16(A, B1, acc[i][1], 0, 0, 0);
    }
  }
#pragma unroll
  for (int i = 0; i < 8; i++) {
    int jb = wave * 128 + i * 16 + quad * 4;
#pragma unroll
    for (int r = 0; r < 4; r++) {
      int j = jb + r;
      float bia = encb[j];
      att1[(size_t)(m0 + lm) * ATT + j]      = f2bf(acc[i][0][r] + bia);
      att1[(size_t)(m0 + 16 + lm) * ATT + j] = f2bf(acc[i][1][r] + bia);
    }
  }
}

// ---------- fused stage 1: step1(t) U fc(t-1) U emb(t)  (929 blocks x 64 thr) ----------
__global__ __launch_bounds__(64) void k_stage1(int t,
    const int* __restrict__ bx, const int* __restrict__ bxlen,
    const u16* __restrict__ W3, const float* __restrict__ decb,
    const float* __restrict__ fbb, const float* __restrict__ bhh,
    const u16* __restrict__ h_bf,
    float* __restrict__ att2, float* __restrict__ gate, float* __restrict__ hWhh,
    const u16* __restrict__ fcW_bf, const float* __restrict__ fcb, float* __restrict__ preds,
    const float* __restrict__ embW, u16* __restrict__ x_bf) {
  int bid = blockIdx.x;
  int lane = threadIdx.x;
  if (bid < 288) {
    if (t >= TT) return;
    int j0 = bid * 16;
    int m = lane & 15, quad = lane >> 4;
    const u16* arow = W3 + (size_t)(j0 + m) * DEC + quad * 8;
    const u16* xb0 = h_bf + (size_t)m * DEC + quad * 8;
    const u16* xb1 = h_bf + (size_t)(16 + m) * DEC + quad * 8;
    f32x4 acc0 = {0.f,0.f,0.f,0.f}, acc1 = {0.f,0.f,0.f,0.f};
    for (int k = 0; k < DEC; k += 32) {
      short8 a = ld_frag(arow + k);
      short8 x0 = ld_frag(xb0 + k);
      short8 x1 = ld_frag(xb1 + k);
      acc0 = __builtin_amdgcn_mfma_f32_16x16x32_bf16(a, x0, acc0, 0, 0, 0);
      acc1 = __builtin_amdgcn_mfma_f32_16x16x32_bf16(a, x1, acc1, 0, 0, 0);
    }
    int jj = j0 + quad * 4;
    int b0 = m, b1 = 16 + m;
#pragma unroll
    for (int r = 0; r < 4; r++) {
      int j = jj + r;
      float v0 = acc0[r], v1 = acc1[r];
      if (j0 < ATT) {
        float bia = decb[j];
        att2[b0 * ATT + j] = v0 + bia;
        att2[b1 * ATT + j] = v1 + bia;
      } else if (j0 < ATT + ENC) {
        int g = j - ATT;
        float bia = fbb[g];
        gate[b0 * ENC + g] = sigf(v0 + bia);
        gate[b1 * ENC + g] = sigf(v1 + bia);
      } else {
        int g = j - ATT - ENC;
        float bia = bhh[g];
        hWhh[b0 * G4 + g] = v0 + bia;
        hWhh[b1 * G4 + g] = v1 + bia;
      }
    }
  } else if (bid < 913) {
    if (t == 0) return;
    int tfc = t - 1;
    int j0 = (bid - 288) * 16;
    int m = lane & 15, quad = lane >> 4;
    const u16* arow = fcW_bf + (size_t)(j0 + m) * DEC + quad * 8;
    const u16* xb0 = h_bf + (size_t)m * DEC + quad * 8;
    const u16* xb1 = h_bf + (size_t)(16 + m) * DEC + quad * 8;
    f32x4 acc0 = {0.f,0.f,0.f,0.f}, acc1 = {0.f,0.f,0.f,0.f};
    for (int k = 0; k < DEC; k += 32) {
      short8 a = ld_frag(arow + k);
      short8 x0 = ld_frag(xb0 + k);
      short8 x1 = ld_frag(xb1 + k);
      acc0 = __builtin_amdgcn_mfma_f32_16x16x32_bf16(a, x0, acc0, 0, 0, 0);
      acc1 = __builtin_amdgcn_mfma_f32_16x16x32_bf16(a, x1, acc1, 0, 0, 0);
    }
    int jj = j0 + quad * 4;
    int b0 = m, b1 = 16 + m;
    bool act0 = (tfc < bxlen[b0]);
    bool act1 = (tfc < bxlen[b1]);
#pragma unroll
    for (int r = 0; r < 4; r++) {
      int j = jj + r;
      float bia = fcb[j];
      preds[((size_t)b0 * TT + tfc) * VV + j] = act0 ? (acc0[r] + bia) : 0.f;
      preds[((size_t)b1 * TT + tfc) * VV + j] = act1 ? (acc1[r] + bia) : 0.f;
    }
  } else {
    if (t >= TT) return;
    int flat = (bid - 913) * 64 + lane;   // 0..1023
    int b = flat >> 5;
    int ch0 = (flat & 31) * 16;
    int tok = bx[b * TT + t];
    const float* e = embW + (size_t)tok * EMB + ch0;
    u16 o[16];
#pragma unroll
    for (int u = 0; u < 16; u++) o[u] = f2bf(e[u]);
    *(uint4*)(x_bf + (size_t)b * KX + ch0)     = *(const uint4*)o;
    *(uint4*)(x_bf + (size_t)b * KX + ch0 + 8) = *(const uint4*)(o + 8);
  }
}

// ---------- fused: e + softmax + awe + x assembly (one block per b, 1024 thr) ----------
__global__ __launch_bounds__(1024) void k_attawe(int t, const int* __restrict__ bxlen,
    const u16* __restrict__ att1, const float* __restrict__ att2,
    const float* __restrict__ faW, const float* __restrict__ fab,
    const u16* __restrict__ imgs_bf, const float* __restrict__ gate,
    float* __restrict__ out_alphas, u16* __restrict__ x_bf) {
  int b = blockIdx.x;
  int tid = threadIdx.x;
  if (t >= bxlen[b]) {
    if (tid < PP) out_alphas[((size_t)b * TT + t) * PP + tid] = 0.f;
    return;
  }
  __shared__ float a2[ATT];
  __shared__ float w_s[ATT];
  __shared__ float alph[PP];
  __shared__ float red1[16], red2[16];
  if (tid < ATT) a2[tid] = att2[b * ATT + tid];
  else w_s[tid - ATT] = faW[tid - ATT];
  __syncthreads();
  // e[p]: team of 4 threads per p, each covering 128 of K=512
  int p = tid >> 2, sub = tid & 3;
  if (p < PP) {
    const uint4* ar = (const uint4*)(att1 + (size_t)(b * PP + p) * ATT + sub * 128);
    int kb = sub * 128;
    float acc = 0.f;
#pragma unroll
    for (int k = 0; k < 128; k += 8) {
      float af[8]; unpack8(ar[k >> 3], af);
#pragma unroll
      for (int u = 0; u < 8; u++) {
        float v = af[u] + a2[kb + k + u];
        acc += fmaxf(v, 0.f) * w_s[kb + k + u];
      }
    }
    acc += __shfl_xor(acc, 1);
    acc += __shfl_xor(acc, 2);
    if (sub == 0) alph[p] = acc + fab[0];   // e value
  }
  __syncthreads();
  // softmax over alph[0..196)
  float v = (tid < PP) ? alph[tid] : -1e30f;
  int lane = tid & 63, wid = tid >> 6;
  float wmax = v;
#pragma unroll
  for (int off = 32; off; off >>= 1) wmax = fmaxf(wmax, __shfl_xor(wmax, off));
  if (lane == 0) red1[wid] = wmax;
  __syncthreads();
  float mx = fmaxf(fmaxf(red1[0], red1[1]), fmaxf(red1[2], red1[3]));
  float ex = (tid < PP) ? __expf(v - mx) : 0.f;
  float wsum = ex;
#pragma unroll
  for (int off = 32; off; off >>= 1) wsum += __shfl_xor(wsum, off);
  if (lane == 0) red2[wid] = wsum;
  __syncthreads();
  float inv = 1.0f / (red2[0] + red2[1] + red2[2] + red2[3]);
  if (tid < PP) {
    float al = ex * inv;
    alph[tid] = al;
    out_alphas[((size_t)b * TT + t) * PP + tid] = al;
  }
  __syncthreads();
  // awe sweep: 1024 threads x 2 ch
  int ch0 = tid * 2;
  const u32* base = (const u32*)(imgs_bf + (size_t)b * PP * ENC + ch0);
  float acc0 = 0.f, acc1 = 0.f;
#pragma unroll 4
  for (int pp = 0; pp < PP; pp++) {
    u32 u = base[(size_t)pp * (ENC / 2)];
    float a = alph[pp];
    acc0 += a * __uint_as_float(u << 16);
    acc1 += a * __uint_as_float(u & 0xffff0000u);
  }
  float2 g = *(const float2*)(gate + b * ENC + ch0);
  u16 o[2] = { f2bf(g.x * acc0), f2bf(g.y * acc1) };
  *(u32*)(x_bf + (size_t)b * KX + EMB + ch0) = *(const u32*)o;
}

// ---------- fused: gates GEMM (full K) + LSTM pointwise (32 blocks x 4 waves) ----------
__global__ __launch_bounds__(256) void k_gateslstm(int t, const int* __restrict__ bxlen,
    const u16* __restrict__ Wih_bf, const float* __restrict__ bih,
    const u16* __restrict__ x_bf, const float* __restrict__ hWhh,
    u16* __restrict__ h_bf, float* __restrict__ c) {
  __shared__ float pre_s[4][16][33];
  int tid = threadIdx.x;
  int wave = tid >> 6, lane = tid & 63;
  int g = blockIdx.x;                    // d-tile [g*16, g*16+16)
  int m = lane & 15, quad = lane >> 4;
  int jbase = wave * 512 + g * 16;       // wave w covers gate section w
  const u16* arow = Wih_bf + (size_t)(jbase + m) * KX + quad * 8;
  const u16* xb0 = x_bf + (size_t)m * KX + quad * 8;
  const u16* xb1 = x_bf + (size_t)(16 + m) * KX + quad * 8;
  f32x4 acc0 = {0.f,0.f,0.f,0.f}, acc1 = {0.f,0.f,0.f,0.f};
#pragma unroll 4
  for (int k = 0; k < KX; k += 32) {
    short8 a = ld_frag(arow + k);
    short8 x0 = ld_frag(xb0 + k);
    short8 x1 = ld_frag(xb1 + k);
    acc0 = __builtin_amdgcn_mfma_f32_16x16x32_bf16(a, x0, acc0, 0, 0, 0);
    acc1 = __builtin_amdgcn_mfma_f32_16x16x32_bf16(a, x1, acc1, 0, 0, 0);
  }
  int dd = quad * 4;
#pragma unroll
  for (int r = 0; r < 4; r++) {
    pre_s[wave][dd + r][m]      = acc0[r];
    pre_s[wave][dd + r][16 + m] = acc1[r];
  }
  __syncthreads();
  for (int i = tid; i < 512; i += 256) {
    int d_idx = i >> 5, b = i & 31;
    if (t >= bxlen[b]) continue;
    int d = g * 16 + d_idx;
    float p0 = pre_s[0][d_idx][b] + bih[d]        + hWhh[b * G4 + d];
    float p1 = pre_s[1][d_idx][b] + bih[512 + d]  + hWhh[b * G4 + 512 + d];
    float p2 = pre_s[2][d_idx][b] + bih[1024 + d] + hWhh[b * G4 + 1024 + d];
    float p3 = pre_s[3][d_idx][b] + bih[1536 + d] + hWhh[b * G4 + 1536 + d];
    float i_ = sigf(p0), f_ = sigf(p1), g_ = tanhf(p2), o_ = sigf(p3);
    float cn = f_ * c[b * DEC + d] + i_ * g_;
    float hn = o_ * tanhf(cn);
    c[b * DEC + d] = cn;
    h_bf[b * DEC + d] = f2bf(hn);
  }
}

extern "C" void kernel_launch(void* const* d_in, const int* in_sizes, int n_in,
                              void* d_out, int out_size, void* d_ws, size_t ws_size,
                              hipStream_t stream) {
  const float* imgs = (const float*)d_in[0];
  const int* bx     = (const int*)d_in[1];
  const int* bxlen  = (const int*)d_in[2];
  const float* embW = (const float*)d_in[3];
  const float* encW = (const float*)d_in[4];
  const float* encb = (const float*)d_in[5];
  const float* decW = (const float*)d_in[6];
  const float* decb = (const float*)d_in[7];
  const float* faW  = (const float*)d_in[8];
  const float* fab  = (const float*)d_in[9];
  const float* ihW  = (const float*)d_in[10];
  const float* ihb  = (const float*)d_in[11];
  const float* icW  = (const float*)d_in[12];
  const float* icb  = (const float*)d_in[13];
  const float* fbW  = (const float*)d_in[14];
  const float* fbb  = (const float*)d_in[15];
  const float* Wih  = (const float*)d_in[16];
  const float* bih  = (const float*)d_in[17];
  const float* Whh  = (const float*)d_in[18];
  const float* bhh  = (const float*)d_in[19];
  const float* fcW  = (const float*)d_in[20];
  const float* fcb  = (const float*)d_in[21];

  float* out_preds  = (float*)d_out;
  float* out_alphas = out_preds + (size_t)BB * TT * VV;

  char* wsb = (char*)d_ws;
  size_t off = 0;
  u16* imgs_bf = (u16*)(wsb + off); off += (size_t)BB * PP * ENC * 2;   // 25.69 MB
  u16* W3_bf   = (u16*)(wsb + off); off += (size_t)4608 * DEC * 2;      // 4.72 MB
  u16* Wih_bf  = (u16*)(wsb + off); off += (size_t)G4 * KX * 2;         // 10.49 MB
  u16* fcW_bf  = (u16*)(wsb + off); off += (size_t)VV * DEC * 2;        // 10.24 MB
  u16* encW_bf = (u16*)(wsb + off); off += (size_t)ATT * ENC * 2;       // 2.00 MB
  u16* att1    = (u16*)(wsb + off);
  u16* W2_bf   = att1;                      // aliased (consumed before att1 write)
  u16* mean_bf = att1 + (size_t)1024 * ENC;
  off += (size_t)BB * PP * ATT * 2;                                     // 6.42 MB
  u16* x_bf    = (u16*)(wsb + off); off += (size_t)BB * KX * 2;         // 160 KB
  u16* h_bf    = (u16*)(wsb + off); off += (size_t)BB * DEC * 2;        // 32 KB
  float* c      = (float*)(wsb + off); off += (size_t)BB * DEC * 4;
  float* att2   = (float*)(wsb + off); off += (size_t)BB * ATT * 4;
  float* gate   = (float*)(wsb + off); off += (size_t)BB * ENC * 4;
  float* hWhh   = (float*)(wsb + off); off += (size_t)BB * G4 * 4;

  // one-time conversions
  k_cvt<<<(BB * PP * ENC) / 2048, 256, 0, stream>>>(imgs, imgs_bf, BB * PP * ENC);
  k_cvt<<<(DEC * DEC) / 2048, 256, 0, stream>>>(decW, W3_bf, DEC * DEC);
  k_cvt<<<(ENC * DEC) / 2048, 256, 0, stream>>>(fbW, W3_bf + (size_t)DEC * DEC, ENC * DEC);
  k_cvt<<<(G4 * DEC) / 2048, 256, 0, stream>>>(Whh, W3_bf + (size_t)(DEC + ENC) * DEC, G4 * DEC);
  k_cvt<<<(G4 * KX) / 2048, 256, 0, stream>>>(Wih, Wih_bf, G4 * KX);
  k_cvt<<<(VV * DEC) / 2048, 256, 0, stream>>>(fcW, fcW_bf, VV * DEC);
  k_cvt<<<(ATT * ENC) / 2048, 256, 0, stream>>>(encW, encW_bf, ATT * ENC);
  k_cvt<<<(DEC * ENC) / 2048, 256, 0, stream>>>(ihW, W2_bf, DEC * ENC);
  k_cvt<<<(DEC * ENC) / 2048, 256, 0, stream>>>(icW, W2_bf + (size_t)DEC * ENC, DEC * ENC);

  k_mean<<<BB * 4, 256, 0, stream>>>(imgs_bf, mean_bf);
  k_init2<<<64, 64, 0, stream>>>(W2_bf, ihb, icb, mean_bf, h_bf, c);
  k_att1<<<(BB * PP) / 32, 256, 0, stream>>>(imgs_bf, encW_bf, encb, att1);

  for (int t = 0; t < TT; t++) {
    k_stage1<<<929, 64, 0, stream>>>(t, bx, bxlen, W3_bf, decb, fbb, bhh, h_bf,
                                     att2, gate, hWhh, fcW_bf, fcb, out_preds, embW, x_bf);
    k_attawe<<<BB, 1024, 0, stream>>>(t, bxlen, att1, att2, faW, fab, imgs_bf, gate,
                                      out_alphas, x_bf);
    k_gateslstm<<<BB, 256, 0, stream>>>(t, bxlen, Wih_bf, bih, x_bf, hWhh, h_bf, c);
  }
  // final fc for t=127 (other parts self-disable at t=TT)
  k_stage1<<<929, 64, 0, stream>>>(TT, bx, bxlen, W3_bf, decb, fbb, bhh, h_bf,
                                   att2, gate, hWhh, fcW_bf, fcb, out_preds, embW, x_bf);
}

// Round 8
// 6265.178 us; speedup vs baseline: 1.4471x; 1.4471x over previous
//
#include <hip/hip_runtime.h>
#include <hip/hip_bf16.h>

#define BB 32
#define TT 128
#define PP 196
#define ENC 2048
#define DEC 512
#define ATT 512
#define EMB 512
#define VV 10000
#define VVP 10240  // padded fcW rows for MFMA tiles
#define G4 2048   // 4*DEC
#define KX 2560   // EMB+ENC

typedef unsigned short u16;
typedef unsigned int u32;
typedef __attribute__((ext_vector_type(8))) short short8;
typedef __attribute__((ext_vector_type(4))) float f32x4;

__device__ __forceinline__ float bf2f(u16 u) { return __uint_as_float(((u32)u) << 16); }
__device__ __forceinline__ u16 f2bf(float f) {
  u32 x = __float_as_uint(f);
  u32 r = (x + 0x7fffu + ((x >> 16) & 1u)) >> 16;
  return (u16)r;
}
__device__ __forceinline__ void unpack8(uint4 v, float* f) {
  f[0] = __uint_as_float(v.x << 16); f[1] = __uint_as_float(v.x & 0xffff0000u);
  f[2] = __uint_as_float(v.y << 16); f[3] = __uint_as_float(v.y & 0xffff0000u);
  f[4] = __uint_as_float(v.z << 16); f[5] = __uint_as_float(v.z & 0xffff0000u);
  f[6] = __uint_as_float(v.w << 16); f[7] = __uint_as_float(v.w & 0xffff0000u);
}
__device__ __forceinline__ void load8(const float* __restrict__ p, float* f) {
  float4 a = ((const float4*)p)[0];
  float4 b = ((const float4*)p)[1];
  f[0] = a.x; f[1] = a.y; f[2] = a.z; f[3] = a.w;
  f[4] = b.x; f[5] = b.y; f[6] = b.z; f[7] = b.w;
}
__device__ __forceinline__ float sigf(float x) { return 1.0f / (1.0f + __expf(-x)); }
__device__ __forceinline__ short8 ld_frag(const u16* __restrict__ p) {
  union { uint4 u; short8 s; } cv;
  cv.u = *(const uint4*)p;
  return cv.s;
}

// ---------- one-time f32 -> bf16 conversion ----------
__global__ __launch_bounds__(256) void k_cvt(const float* __restrict__ src, u16* __restrict__ dst, int n) {
  int i0 = (blockIdx.x * 256 + threadIdx.x) * 8;
  if (i0 >= n) return;
  float f[8]; load8(src + i0, f);
  u16 o[8];
#pragma unroll
  for (int u = 0; u < 8; u++) o[u] = f2bf(f[u]);
  *(uint4*)(dst + i0) = *(const uint4*)o;
}

// ---------- one-time: gather emb rows for all (b,t) -> x_emb_all bf16 (4096 x 512) ----------
__global__ __launch_bounds__(256) void k_emball(const int* __restrict__ bx,
    const float* __restrict__ embW, u16* __restrict__ xemb) {
  int flat = blockIdx.x * 256 + threadIdx.x;   // 262144 = 4096 rows x 64 chunks
  int row = flat >> 6;
  int c8 = (flat & 63) * 8;
  int tok = bx[row];                            // row = b*TT + t, bx flat is same
  const float* e = embW + (size_t)tok * EMB + c8;
  float f[8]; load8(e, f);
  u16 o[8];
#pragma unroll
  for (int u = 0; u < 8; u++) o[u] = f2bf(f[u]);
  *(uint4*)(xemb + (size_t)row * EMB + c8) = *(const uint4*)o;
}

// ---------- mean over p: imgs_bf -> mean_bf (32 x 2048 bf16) ----------
__global__ __launch_bounds__(256) void k_mean(const u16* __restrict__ imgs_bf, u16* __restrict__ mean_bf) {
  int b = blockIdx.x >> 2, chunk = blockIdx.x & 3;
  int ch0 = chunk * 512 + threadIdx.x * 2;
  const u32* base = (const u32*)(imgs_bf + (size_t)b * PP * ENC + ch0);
  float a0 = 0.f, a1 = 0.f;
#pragma unroll 4
  for (int p = 0; p < PP; p++) {
    u32 u = base[(size_t)p * (ENC / 2)];
    a0 += __uint_as_float(u << 16);
    a1 += __uint_as_float(u & 0xffff0000u);
  }
  const float inv = 1.0f / PP;
  u16 o[2] = { f2bf(a0 * inv), f2bf(a1 * inv) };
  *(u32*)(mean_bf + b * ENC + ch0) = *(const u32*)o;
}

// ---------- init via MFMA: [h0;c0] = mean @ [ihW;icW]^T + b ----------
__global__ __launch_bounds__(64) void k_init2(const u16* __restrict__ W2_bf,
    const float* __restrict__ ihb, const float* __restrict__ icb,
    const u16* __restrict__ mean_bf, u16* __restrict__ h_bf, float* __restrict__ c) {
  int lane = threadIdx.x;
  int j0 = blockIdx.x * 16;
  int m = lane & 15, quad = lane >> 4;
  const u16* arow = W2_bf + (size_t)(j0 + m) * ENC + quad * 8;
  const u16* xb0 = mean_bf + (size_t)m * ENC + quad * 8;
  const u16* xb1 = mean_bf + (size_t)(16 + m) * ENC + quad * 8;
  f32x4 acc0 = {0.f,0.f,0.f,0.f}, acc1 = {0.f,0.f,0.f,0.f};
  for (int k = 0; k < ENC; k += 32) {
    short8 a = ld_frag(arow + k);
    short8 x0 = ld_frag(xb0 + k);
    short8 x1 = ld_frag(xb1 + k);
    acc0 = __builtin_amdgcn_mfma_f32_16x16x32_bf16(a, x0, acc0, 0, 0, 0);
    acc1 = __builtin_amdgcn_mfma_f32_16x16x32_bf16(a, x1, acc1, 0, 0, 0);
  }
  int jj = j0 + quad * 4;
  int b0 = m, b1 = 16 + m;
#pragma unroll
  for (int r = 0; r < 4; r++) {
    int j = jj + r;
    if (j < 512) {
      float bia = ihb[j];
      h_bf[b0 * DEC + j] = f2bf(acc0[r] + bia);
      h_bf[b1 * DEC + j] = f2bf(acc1[r] + bia);
    } else {
      int g = j - 512;
      float bia = icb[g];
      c[b0 * DEC + g] = acc0[r] + bia;
      c[b1 * DEC + g] = acc1[r] + bia;
    }
  }
}

// ---------- att1 via MFMA: imgs_bf(6272x2048) @ encW^T -> att1 bf16 ----------
__global__ __launch_bounds__(256) void k_att1(const u16* __restrict__ imgs_bf,
    const u16* __restrict__ encW_bf, const float* __restrict__ encb, u16* __restrict__ att1) {
  int tid = threadIdx.x;
  int wave = tid >> 6, lane = tid & 63;
  int m0 = blockIdx.x * 32;
  int lm = lane & 15, quad = lane >> 4;
  const u16* b0p = imgs_bf + (size_t)(m0 + lm) * ENC + quad * 8;
  const u16* b1p = imgs_bf + (size_t)(m0 + 16 + lm) * ENC + quad * 8;
  const u16* arow = encW_bf + (size_t)(wave * 128 + lm) * ENC + quad * 8;
  f32x4 acc[8][2];
#pragma unroll
  for (int i = 0; i < 8; i++) { acc[i][0] = (f32x4){0.f,0.f,0.f,0.f}; acc[i][1] = (f32x4){0.f,0.f,0.f,0.f}; }
  for (int k = 0; k < ENC; k += 32) {
    short8 B0 = ld_frag(b0p + k);
    short8 B1 = ld_frag(b1p + k);
#pragma unroll
    for (int i = 0; i < 8; i++) {
      short8 A = ld_frag(arow + (size_t)i * 16 * ENC + k);
      acc[i][0] = __builtin_amdgcn_mfma_f32_16x16x32_bf16(A, B0, acc[i][0], 0, 0, 0);
      acc[i][1] = __builtin_amdgcn_mfma_f32_16x16x32_bf16(A, B1, acc[i][1], 0, 0, 0);
    }
  }
#pragma unroll
  for (int i = 0; i < 8; i++) {
    int jb = wave * 128 + i * 16 + quad * 4;
#pragma unroll
    for (int r = 0; r < 4; r++) {
      int j = jb + r;
      float bia = encb[j];
      att1[(size_t)(m0 + lm) * ATT + j]      = f2bf(acc[i][0][r] + bia);
      att1[(size_t)(m0 + 16 + lm) * ATT + j] = f2bf(acc[i][1][r] + bia);
    }
  }
}

// ---------- per-step: step1 MFMA GEMM W3=[dec|fb|whh] (4608x512) x h^T (288 blocks x 64) ----------
__global__ __launch_bounds__(64) void k_step1(const u16* __restrict__ W3,
    const float* __restrict__ decb, const float* __restrict__ fbb, const float* __restrict__ bhh,
    const u16* __restrict__ h_bf,
    float* __restrict__ att2, float* __restrict__ gate, float* __restrict__ hWhh) {
  int lane = threadIdx.x;
  int j0 = blockIdx.x * 16;
  int m = lane & 15, quad = lane >> 4;
  const u16* arow = W3 + (size_t)(j0 + m) * DEC + quad * 8;
  const u16* xb0 = h_bf + (size_t)m * DEC + quad * 8;
  const u16* xb1 = h_bf + (size_t)(16 + m) * DEC + quad * 8;
  f32x4 acc0 = {0.f,0.f,0.f,0.f}, acc1 = {0.f,0.f,0.f,0.f};
  for (int k = 0; k < DEC; k += 32) {
    short8 a = ld_frag(arow + k);
    short8 x0 = ld_frag(xb0 + k);
    short8 x1 = ld_frag(xb1 + k);
    acc0 = __builtin_amdgcn_mfma_f32_16x16x32_bf16(a, x0, acc0, 0, 0, 0);
    acc1 = __builtin_amdgcn_mfma_f32_16x16x32_bf16(a, x1, acc1, 0, 0, 0);
  }
  int jj = j0 + quad * 4;
  int b0 = m, b1 = 16 + m;
#pragma unroll
  for (int r = 0; r < 4; r++) {
    int j = jj + r;
    float v0 = acc0[r], v1 = acc1[r];
    if (j0 < ATT) {
      float bia = decb[j];
      att2[b0 * ATT + j] = v0 + bia;
      att2[b1 * ATT + j] = v1 + bia;
    } else if (j0 < ATT + ENC) {
      int g = j - ATT;
      float bia = fbb[g];
      gate[b0 * ENC + g] = sigf(v0 + bia);
      gate[b1 * ENC + g] = sigf(v1 + bia);
    } else {
      int g = j - ATT - ENC;
      float bia = bhh[g];
      hWhh[b0 * G4 + g] = v0 + bia;
      hWhh[b1 * G4 + g] = v1 + bia;
    }
  }
}

// ---------- per-step: e, softmax, alpha (one block per b) ----------
__global__ __launch_bounds__(256) void k_att(int t, const int* __restrict__ bxlen,
    const u16* __restrict__ att1, const float* __restrict__ att2,
    const float* __restrict__ faW, const float* __restrict__ fab,
    float* __restrict__ alpha_ws, float* __restrict__ out_alphas) {
  int b = blockIdx.x;
  int tid = threadIdx.x;
  if (t >= bxlen[b]) {
    if (tid < PP) out_alphas[((size_t)b * TT + t) * PP + tid] = 0.f;
    return;
  }
  __shared__ float a2[ATT];
  __shared__ float w_s[ATT];
  __shared__ float redw[4], redw2[4];
  for (int i = tid; i < ATT; i += 256) { a2[i] = att2[b * ATT + i]; w_s[i] = faW[i]; }
  __syncthreads();
  float e = -1e30f;
  if (tid < PP) {
    const uint4* ar = (const uint4*)(att1 + (size_t)(b * PP + tid) * ATT);
    float acc = 0.f;
    for (int k = 0; k < ATT; k += 8) {
      float af[8]; unpack8(ar[k >> 3], af);
#pragma unroll
      for (int u = 0; u < 8; u++) {
        float v = af[u] + a2[k + u];
        acc += fmaxf(v, 0.f) * w_s[k + u];
      }
    }
    e = acc + fab[0];
  }
  int lane = tid & 63, wid = tid >> 6;
  float wmax = e;
#pragma unroll
  for (int off = 32; off; off >>= 1) wmax = fmaxf(wmax, __shfl_xor(wmax, off));
  if (lane == 0) redw[wid] = wmax;
  __syncthreads();
  float mx = fmaxf(fmaxf(redw[0], redw[1]), fmaxf(redw[2], redw[3]));
  float ex = (tid < PP) ? __expf(e - mx) : 0.f;
  float wsum = ex;
#pragma unroll
  for (int off = 32; off; off >>= 1) wsum += __shfl_xor(wsum, off);
  if (lane == 0) redw2[wid] = wsum;
  __syncthreads();
  float inv = 1.0f / (redw2[0] + redw2[1] + redw2[2] + redw2[3]);
  if (tid < PP) {
    float al = ex * inv;
    alpha_ws[b * PP + tid] = al;
    out_alphas[((size_t)b * TT + t) * PP + tid] = al;
  }
}

// ---------- per-step: awe = alpha . imgs; x_awe = gate*awe (bf16, 32x2048) ----------
__global__ __launch_bounds__(256) void k_awe(int t, const int* __restrict__ bxlen,
    const u16* __restrict__ imgs_bf, const float* __restrict__ alpha_ws,
    const float* __restrict__ gate, u16* __restrict__ x_awe) {
  int b = blockIdx.x >> 2, chunk = blockIdx.x & 3;
  if (t >= bxlen[b]) return;
  __shared__ float al[PP];
  int tid = threadIdx.x;
  if (tid < PP) al[tid] = alpha_ws[b * PP + tid];
  __syncthreads();
  int ch0 = chunk * 512 + tid * 2;
  const u32* base = (const u32*)(imgs_bf + (size_t)b * PP * ENC + ch0);
  float acc0 = 0.f, acc1 = 0.f;
#pragma unroll 4
  for (int p = 0; p < PP; p++) {
    u32 u = base[(size_t)p * (ENC / 2)];
    float a = al[p];
    acc0 += a * __uint_as_float(u << 16);
    acc1 += a * __uint_as_float(u & 0xffff0000u);
  }
  float2 g = *(const float2*)(gate + b * ENC + ch0);
  u16 o[2] = { f2bf(g.x * acc0), f2bf(g.y * acc1) };
  *(u32*)(x_awe + (size_t)b * ENC + ch0) = *(const u32*)o;
}

// ---------- per-step: gates partials via MFMA, uniform split-K 5x512 ----------
// y=0: emb K-chunk (from x_emb_all at step t); y=1..4: awe K-chunks
__global__ __launch_bounds__(64) void k_gates(int t, const u16* __restrict__ Wih_bf,
    const u16* __restrict__ xemb, const u16* __restrict__ x_awe,
    float* __restrict__ gates_p) {
  int lane = threadIdx.x;
  int j0 = blockIdx.x * 16;
  int y = blockIdx.y;
  int kofs = y * 512;
  int m = lane & 15, quad = lane >> 4;
  const u16* arow = Wih_bf + (size_t)(j0 + m) * KX + kofs + quad * 8;
  const u16 *b0p, *b1p;
  if (y == 0) {
    b0p = xemb + ((size_t)m * TT + t) * EMB + quad * 8;
    b1p = xemb + ((size_t)(16 + m) * TT + t) * EMB + quad * 8;
  } else {
    int ao = kofs - 512;
    b0p = x_awe + (size_t)m * ENC + ao + quad * 8;
    b1p = x_awe + (size_t)(16 + m) * ENC + ao + quad * 8;
  }
  f32x4 acc0 = {0.f,0.f,0.f,0.f}, acc1 = {0.f,0.f,0.f,0.f};
  for (int k = 0; k < 512; k += 32) {
    short8 a = ld_frag(arow + k);
    short8 x0 = ld_frag(b0p + k);
    short8 x1 = ld_frag(b1p + k);
    acc0 = __builtin_amdgcn_mfma_f32_16x16x32_bf16(a, x0, acc0, 0, 0, 0);
    acc1 = __builtin_amdgcn_mfma_f32_16x16x32_bf16(a, x1, acc1, 0, 0, 0);
  }
  float* gp = gates_p + (size_t)y * BB * G4;
  int jj = j0 + quad * 4;
  int b0 = m, b1 = 16 + m;
#pragma unroll
  for (int r = 0; r < 4; r++) {
    int j = jj + r;
    gp[b0 * G4 + j] = acc0[r];
    gp[b1 * G4 + j] = acc1[r];
  }
}

// ---------- per-step: LSTM pointwise (sums 5 split-K partials), writes h + h_hist ----------
__global__ __launch_bounds__(256) void k_lstm(int t, const int* __restrict__ bxlen,
    const float* __restrict__ gates_p, const float* __restrict__ bih,
    const float* __restrict__ hWhh,
    u16* __restrict__ h_bf, float* __restrict__ c, u16* __restrict__ h_hist) {
  int idx = blockIdx.x * 256 + threadIdx.x;
  int b = idx >> 9, d = idx & 511;
  if (t >= bxlen[b]) return;
  float pre[4];
#pragma unroll
  for (int g = 0; g < 4; g++) {
    int j = g * 512 + d;
    float s = bih[j] + hWhh[b * G4 + j];
#pragma unroll
    for (int cc = 0; cc < 5; cc++) s += gates_p[(size_t)cc * BB * G4 + b * G4 + j];
    pre[g] = s;
  }
  float i_ = sigf(pre[0]);
  float f_ = sigf(pre[1]);
  float g_ = tanhf(pre[2]);
  float o_ = sigf(pre[3]);
  float cn = f_ * c[b * DEC + d] + i_ * g_;
  float hn = o_ * tanhf(cn);
  c[b * DEC + d] = cn;
  u16 hb = f2bf(hn);
  h_bf[b * DEC + d] = hb;
  h_hist[((size_t)b * TT + t) * DEC + d] = hb;
}

// ---------- batched fc: preds = h_hist(4096x512) @ fcW^T + fcb, masked ----------
// grid (128, 20) x 256 thr: m-block 32 rows, n-block 512 j (4 waves x 128 j)
__global__ __launch_bounds__(256) void k_fcall(const int* __restrict__ bxlen,
    const u16* __restrict__ fcW_bf, const float* __restrict__ fcb,
    const u16* __restrict__ h_hist, float* __restrict__ preds) {
  int tid = threadIdx.x;
  int wave = tid >> 6, lane = tid & 63;
  int m0 = blockIdx.x * 32;
  int jbase = blockIdx.y * 512 + wave * 128;
  int lm = lane & 15, quad = lane >> 4;
  const u16* b0p = h_hist + (size_t)(m0 + lm) * DEC + quad * 8;
  const u16* b1p = h_hist + (size_t)(m0 + 16 + lm) * DEC + quad * 8;
  const u16* arow = fcW_bf + (size_t)(jbase + lm) * DEC + quad * 8;
  f32x4 acc[8][2];
#pragma unroll
  for (int i = 0; i < 8; i++) { acc[i][0] = (f32x4){0.f,0.f,0.f,0.f}; acc[i][1] = (f32x4){0.f,0.f,0.f,0.f}; }
  for (int k = 0; k < DEC; k += 32) {
    short8 B0 = ld_frag(b0p + k);
    short8 B1 = ld_frag(b1p + k);
#pragma unroll
    for (int i = 0; i < 8; i++) {
      short8 A = ld_frag(arow + (size_t)i * 16 * DEC + k);
      acc[i][0] = __builtin_amdgcn_mfma_f32_16x16x32_bf16(A, B0, acc[i][0], 0, 0, 0);
      acc[i][1] = __builtin_amdgcn_mfma_f32_16x16x32_bf16(A, B1, acc[i][1], 0, 0, 0);
    }
  }
  int row0 = m0 + lm, row1 = m0 + 16 + lm;
  bool act0 = ((row0 & 127) < bxlen[row0 >> 7]);
  bool act1 = ((row1 & 127) < bxlen[row1 >> 7]);
#pragma unroll
  for (int i = 0; i < 8; i++) {
    int jb = jbase + i * 16 + quad * 4;
#pragma unroll
    for (int r = 0; r < 4; r++) {
      int j = jb + r;
      if (j < VV) {
        float bia = fcb[j];
        preds[(size_t)row0 * VV + j] = act0 ? (acc[i][0][r] + bia) : 0.f;
        preds[(size_t)row1 * VV + j] = act1 ? (acc[i][1][r] + bia) : 0.f;
      }
    }
  }
}

extern "C" void kernel_launch(void* const* d_in, const int* in_sizes, int n_in,
                              void* d_out, int out_size, void* d_ws, size_t ws_size,
                              hipStream_t stream) {
  const float* imgs = (const float*)d_in[0];
  const int* bx     = (const int*)d_in[1];
  const int* bxlen  = (const int*)d_in[2];
  const float* embW = (const float*)d_in[3];
  const float* encW = (const float*)d_in[4];
  const float* encb = (const float*)d_in[5];
  const float* decW = (const float*)d_in[6];
  const float* decb = (const float*)d_in[7];
  const float* faW  = (const float*)d_in[8];
  const float* fab  = (const float*)d_in[9];
  const float* ihW  = (const float*)d_in[10];
  const float* ihb  = (const float*)d_in[11];
  const float* icW  = (const float*)d_in[12];
  const float* icb  = (const float*)d_in[13];
  const float* fbW  = (const float*)d_in[14];
  const float* fbb  = (const float*)d_in[15];
  const float* Wih  = (const float*)d_in[16];
  const float* bih  = (const float*)d_in[17];
  const float* Whh  = (const float*)d_in[18];
  const float* bhh  = (const float*)d_in[19];
  const float* fcW  = (const float*)d_in[20];
  const float* fcb  = (const float*)d_in[21];

  float* out_preds  = (float*)d_out;
  float* out_alphas = out_preds + (size_t)BB * TT * VV;

  char* wsb = (char*)d_ws;
  size_t off = 0;
  u16* imgs_bf = (u16*)(wsb + off); off += (size_t)BB * PP * ENC * 2;   // 25.69 MB
  u16* W3_bf   = (u16*)(wsb + off); off += (size_t)4608 * DEC * 2;      // 4.72 MB
  u16* Wih_bf  = (u16*)(wsb + off); off += (size_t)G4 * KX * 2;         // 10.49 MB
  u16* fcW_bf  = (u16*)(wsb + off); off += (size_t)VVP * DEC * 2;       // 10.49 MB (padded)
  u16* encW_bf = (u16*)(wsb + off); off += (size_t)ATT * ENC * 2;       // 2.00 MB
  u16* att1    = (u16*)(wsb + off);
  u16* W2_bf   = att1;                      // aliased (consumed before att1 write)
  u16* mean_bf = att1 + (size_t)1024 * ENC;
  off += (size_t)BB * PP * ATT * 2;                                     // 6.42 MB
  u16* xemb    = (u16*)(wsb + off); off += (size_t)BB * TT * EMB * 2;   // 4.19 MB
  u16* h_hist  = (u16*)(wsb + off); off += (size_t)BB * TT * DEC * 2;   // 4.19 MB
  u16* x_awe   = (u16*)(wsb + off); off += (size_t)BB * ENC * 2;        // 128 KB
  u16* h_bf    = (u16*)(wsb + off); off += (size_t)BB * DEC * 2;        // 32 KB
  float* c      = (float*)(wsb + off); off += (size_t)BB * DEC * 4;
  float* att2   = (float*)(wsb + off); off += (size_t)BB * ATT * 4;
  float* gate   = (float*)(wsb + off); off += (size_t)BB * ENC * 4;
  float* hWhh   = (float*)(wsb + off); off += (size_t)BB * G4 * 4;
  float* gates_p = (float*)(wsb + off); off += (size_t)5 * BB * G4 * 4; // 1.31 MB
  float* alpha  = (float*)(wsb + off); off += (size_t)BB * PP * 4;

  // one-time conversions + hoists
  k_cvt<<<(BB * PP * ENC) / 2048, 256, 0, stream>>>(imgs, imgs_bf, BB * PP * ENC);
  k_cvt<<<(DEC * DEC) / 2048, 256, 0, stream>>>(decW, W3_bf, DEC * DEC);
  k_cvt<<<(ENC * DEC) / 2048, 256, 0, stream>>>(fbW, W3_bf + (size_t)DEC * DEC, ENC * DEC);
  k_cvt<<<(G4 * DEC) / 2048, 256, 0, stream>>>(Whh, W3_bf + (size_t)(DEC + ENC) * DEC, G4 * DEC);
  k_cvt<<<(G4 * KX) / 2048, 256, 0, stream>>>(Wih, Wih_bf, G4 * KX);
  k_cvt<<<(VV * DEC) / 2048, 256, 0, stream>>>(fcW, fcW_bf, VV * DEC);
  k_cvt<<<(ATT * ENC) / 2048, 256, 0, stream>>>(encW, encW_bf, ATT * ENC);
  k_cvt<<<(DEC * ENC) / 2048, 256, 0, stream>>>(ihW, W2_bf, DEC * ENC);
  k_cvt<<<(DEC * ENC) / 2048, 256, 0, stream>>>(icW, W2_bf + (size_t)DEC * ENC, DEC * ENC);
  k_emball<<<(BB * TT * EMB / 8) / 256, 256, 0, stream>>>(bx, embW, xemb);

  k_mean<<<BB * 4, 256, 0, stream>>>(imgs_bf, mean_bf);
  k_init2<<<64, 64, 0, stream>>>(W2_bf, ihb, icb, mean_bf, h_bf, c);
  k_att1<<<(BB * PP) / 32, 256, 0, stream>>>(imgs_bf, encW_bf, encb, att1);

  for (int t = 0; t < TT; t++) {
    k_step1<<<4608 / 16, 64, 0, stream>>>(W3_bf, decb, fbb, bhh, h_bf, att2, gate, hWhh);
    k_att<<<BB, 256, 0, stream>>>(t, bxlen, att1, att2, faW, fab, alpha, out_alphas);
    k_awe<<<BB * 4, 256, 0, stream>>>(t, bxlen, imgs_bf, alpha, gate, x_awe);
    k_gates<<<dim3(G4 / 16, 5), 64, 0, stream>>>(t, Wih_bf, xemb, x_awe, gates_p);
    k_lstm<<<(BB * DEC) / 256, 256, 0, stream>>>(t, bxlen, gates_p, bih, hWhh, h_bf, c, h_hist);
  }
  // batched fc over all (b,t)
  k_fcall<<<dim3((BB * TT) / 32, 20), 256, 0, stream>>>(bxlen, fcW_bf, fcb, h_hist, out_preds);
}